// Round 1
// baseline (1803.838 us; speedup 1.0000x reference)
//
#include <hip/hip_runtime.h>

// ---------------------------------------------------------------------------
// Attention_17703855194398: AdaRMSNorm -> QKV -> per-head RMS+RoPE -> SDPA -> out
// B=2, L=2048, D=2048, NH=32, HD=64, DC=2048
// Strategy round 1: bf16 MFMA GEMMs (m97 structure), fp32 tiled attention.
// ---------------------------------------------------------------------------

typedef __bf16 bf16x8 __attribute__((ext_vector_type(8)));
typedef float  f32x4  __attribute__((ext_vector_type(4)));

#define EPS_F32 1.1920929e-07f

__device__ __forceinline__ float bf2f(unsigned int u16) {
  union { unsigned int i; float f; } v; v.i = (u16 & 0xffffu) << 16; return v.f;
}
__device__ __forceinline__ unsigned short f2bf(float f) {
  union { float f; unsigned int i; } v; v.f = f;
  unsigned int r = v.i + 0x7fffu + ((v.i >> 16) & 1u);  // RNE
  return (unsigned short)(r >> 16);
}

// async global->LDS, 16B per lane. LDS dest is wave-uniform base + lane*16,
// so lds pointers must be contiguous in lane order (they are: &arr[tid*8]).
__device__ __forceinline__ void gload16(const void* g, void* l) {
  __builtin_amdgcn_global_load_lds(
      (const __attribute__((address_space(1))) unsigned int*)(unsigned long long)g,
      (__attribute__((address_space(3))) unsigned int*)(unsigned int)(unsigned long long)l,
      16, 0, 0);
}

// ---------------------------------------------------------------------------
// 1) ada GEMM: ss[b,j] = sum_k cond[b,k] * w_ada[j,k]   (fp32, tiny)
//    one wave per (b,j); lanes stride k as float4
// ---------------------------------------------------------------------------
__global__ __launch_bounds__(256) void ada_gemm_kernel(
    const float* __restrict__ cond, const float* __restrict__ w_ada,
    float* __restrict__ ss)
{
  const int lane = threadIdx.x & 63;
  const int gw = blockIdx.x * 4 + (threadIdx.x >> 6);   // 0..8191
  const int b = gw >> 12;
  const int j = gw & 4095;
  const float4* wr = (const float4*)(w_ada + j * 2048);
  const float4* cr = (const float4*)(cond + b * 2048);
  float acc = 0.f;
  #pragma unroll
  for (int k4 = 0; k4 < 8; ++k4) {
    float4 w = wr[lane + k4 * 64];
    float4 c = cr[lane + k4 * 64];
    acc += w.x * c.x + w.y * c.y + w.z * c.z + w.w * c.w;
  }
  #pragma unroll
  for (int off = 1; off < 64; off <<= 1) acc += __shfl_xor(acc, off);
  if (lane == 0) ss[b * 4096 + j] = acc;
}

// ---------------------------------------------------------------------------
// 2) AdaRMSNorm: h = rms_norm(x)*(1+scale) + shift, write bf16
//    one block per row (b,l); 256 threads x 8 elems
// ---------------------------------------------------------------------------
__global__ __launch_bounds__(256) void ada_rms_kernel(
    const float* __restrict__ x, const float* __restrict__ ss,
    unsigned short* __restrict__ H)
{
  const int row = blockIdx.x;          // b*2048 + l
  const int b = row >> 11;
  const int tid = threadIdx.x;
  const int lane = tid & 63, wave = tid >> 6;
  const float* xr = x + (size_t)row * 2048;
  float4 v0 = ((const float4*)xr)[tid * 2];
  float4 v1 = ((const float4*)xr)[tid * 2 + 1];
  float ssq = v0.x*v0.x + v0.y*v0.y + v0.z*v0.z + v0.w*v0.w
            + v1.x*v1.x + v1.y*v1.y + v1.z*v1.z + v1.w*v1.w;
  #pragma unroll
  for (int off = 1; off < 64; off <<= 1) ssq += __shfl_xor(ssq, off);
  __shared__ float red[4];
  if (lane == 0) red[wave] = ssq;
  __syncthreads();
  const float tot = red[0] + red[1] + red[2] + red[3];
  const float r = rsqrtf(tot * (1.f / 2048.f) + EPS_F32);
  const int c0 = tid * 8;
  const float* sh = ss + b * 4096;        // shift at [0,2048), scale at [2048,4096)
  float xv[8] = {v0.x, v0.y, v0.z, v0.w, v1.x, v1.y, v1.z, v1.w};
  unsigned int pk[4];
  #pragma unroll
  for (int p = 0; p < 4; ++p) {
    const int c = c0 + p * 2;
    float h0 = xv[p*2+0] * r * (1.f + sh[2048 + c])     + sh[c];
    float h1 = xv[p*2+1] * r * (1.f + sh[2048 + c + 1]) + sh[c + 1];
    pk[p] = (unsigned int)f2bf(h0) | ((unsigned int)f2bf(h1) << 16);
  }
  *(uint4*)&H[(size_t)row * 2048 + c0] = make_uint4(pk[0], pk[1], pk[2], pk[3]);
}

// ---------------------------------------------------------------------------
// 3) fp32 -> bf16 weight cast (grid-stride over float4)
// ---------------------------------------------------------------------------
__global__ __launch_bounds__(256) void cast_kernel(
    const float* __restrict__ src, unsigned short* __restrict__ dst, int n4)
{
  const int i = blockIdx.x * 256 + threadIdx.x;
  if (i >= n4) return;
  float4 v = ((const float4*)src)[i];
  unsigned int p0 = (unsigned int)f2bf(v.x) | ((unsigned int)f2bf(v.y) << 16);
  unsigned int p1 = (unsigned int)f2bf(v.z) | ((unsigned int)f2bf(v.w) << 16);
  *(uint2*)&dst[(size_t)i * 4] = make_uint2(p0, p1);
}

// ---------------------------------------------------------------------------
// 4) bf16 MFMA GEMM, C[M,N] = A[M,K] @ Bw[N,K]^T  (m97 structure)
//    128x128 tile, BK=32, 4 waves of 64x64, 16x16x32 MFMA.
//    A/B frag: elem = T[lane&15][ (lane>>4)*8 + j ]   (row-major [*,K] tiles)
//    C/D:      col = lane&15, row = (lane>>4)*4 + reg   [measured m89/m91]
// ---------------------------------------------------------------------------
template <int WRITE_BF16>
__global__ __launch_bounds__(256) void gemm_bt_kernel(
    const unsigned short* __restrict__ A,   // [M,K] bf16
    const unsigned short* __restrict__ Bw,  // [N,K] bf16
    void* __restrict__ Cv,                  // [M,N] bf16 or f32
    int M, int N, int K)
{
  __shared__ unsigned short As[128 * 32];
  __shared__ unsigned short Bs[128 * 32];
  const int tid  = threadIdx.x;
  const int lane = tid & 63;
  const int wave = tid >> 6;
  const int wm = (wave >> 1) * 64;
  const int wn = (wave & 1) * 64;
  const int bm = blockIdx.y * 128;
  const int bn = blockIdx.x * 128;

  f32x4 acc[4][4] = {};

  // staging map: thread covers As elems [tid*8 .. +8) (chunk0) and +2048 (chunk1)
  const int sm = tid >> 2;            // tile row, chunk0
  const int sk = (tid & 3) * 8;       // k within tile
  const unsigned short* Ap  = A  + (size_t)(bm + sm) * K + sk;
  const unsigned short* Ap2 = Ap + (size_t)64 * K;
  const unsigned short* Bp  = Bw + (size_t)(bn + sm) * K + sk;
  const unsigned short* Bp2 = Bp + (size_t)64 * K;
  unsigned short* lA  = &As[tid * 8];
  unsigned short* lA2 = &As[tid * 8 + 2048];
  unsigned short* lB  = &Bs[tid * 8];
  unsigned short* lB2 = &Bs[tid * 8 + 2048];

  const int fr = lane & 15;
  const int fk = (lane >> 4) * 8;

  for (int k0 = 0; k0 < K; k0 += 32) {
    __syncthreads();                     // prior-iter LDS reads done
    gload16(Ap  + k0, lA);
    gload16(Ap2 + k0, lA2);
    gload16(Bp  + k0, lB);
    gload16(Bp2 + k0, lB2);
    __syncthreads();                     // drains vmcnt before barrier

    bf16x8 af[4], bfr[4];
    #pragma unroll
    for (int i = 0; i < 4; ++i)
      af[i] = *(const bf16x8*)&As[(wm + i * 16 + fr) * 32 + fk];
    #pragma unroll
    for (int j = 0; j < 4; ++j)
      bfr[j] = *(const bf16x8*)&Bs[(wn + j * 16 + fr) * 32 + fk];
    #pragma unroll
    for (int i = 0; i < 4; ++i)
      #pragma unroll
      for (int j = 0; j < 4; ++j)
        acc[i][j] = __builtin_amdgcn_mfma_f32_16x16x32_bf16(af[i], bfr[j], acc[i][j], 0, 0, 0);
  }

  const int cr = (lane >> 4) * 4;
  const int cc = lane & 15;
  #pragma unroll
  for (int i = 0; i < 4; ++i) {
    #pragma unroll
    for (int j = 0; j < 4; ++j) {
      #pragma unroll
      for (int r = 0; r < 4; ++r) {
        const int row = bm + wm + i * 16 + cr + r;
        const int col = bn + wn + j * 16 + cc;
        if (WRITE_BF16)
          ((unsigned short*)Cv)[(size_t)row * N + col] = f2bf(acc[i][j][r]);
        else
          ((float*)Cv)[(size_t)row * N + col] = acc[i][j][r];
      }
    }
  }
}

// ---------------------------------------------------------------------------
// 5) per-head RMSNorm(qk_w) + RoPE on q,k in place (bf16 qkv buffer)
//    one wave per (b,h,l); lane = hd
// ---------------------------------------------------------------------------
__global__ __launch_bounds__(256) void qk_rope_kernel(
    unsigned short* __restrict__ QKV, const float* __restrict__ rope,
    const float* __restrict__ qk_w)
{
  const int lane = threadIdx.x & 63;
  const int gid = blockIdx.x * 4 + (threadIdx.x >> 6);  // 0..131071
  const int l = gid & 2047;
  const int h = (gid >> 11) & 31;
  const int b = gid >> 16;
  const int base = (b * 2048 + l) * 6144 + h * 64 + lane;
  const float r0 = rope[l * 64 + lane];
  const float r1 = rope[131072 + l * 64 + lane];
  const float w  = qk_w[lane];
  #pragma unroll
  for (int t = 0; t < 2; ++t) {        // t=0: q, t=1: k
    const int idx = base + 2048 * t;
    const float v = bf2f(QKV[idx]);
    float sq = v * v;
    #pragma unroll
    for (int off = 1; off < 64; off <<= 1) sq += __shfl_xor(sq, off);
    const float vn = v * rsqrtf(sq * (1.f / 64.f) + EPS_F32) * w;
    const float vp = __shfl_xor(vn, 1);
    const float vh = (lane & 1) ? vp : -vp;   // x_hat: even=-x[odd], odd=+x[even]
    QKV[idx] = f2bf(vn * r0 + vh * r1);
  }
}

// ---------------------------------------------------------------------------
// 6) fp32 tiled attention w/ online softmax.
//    block = (b,h,qtile of 64 rows); thread (qr = tid>>2, kg = tid&3).
//    K/V tiles (64x64) in LDS stride 68 (16B-aligned, 2-way-max conflicts).
//    S: thread does 16 kpos = kg + 4*kk over its q row (q in 64 regs).
//    P reuses Ks LDS. O: thread owns dims [kg*16, kg*16+16).
// ---------------------------------------------------------------------------
__global__ __launch_bounds__(256) void attn_kernel(
    const unsigned short* __restrict__ QKV,   // [4096][6144] bf16 (q,k roped)
    unsigned short* __restrict__ O)           // [4096][2048] bf16
{
  __shared__ float Ks[64 * 68];   // also reused as P[qr][kpos]
  __shared__ float Vs[64 * 68];
  const int tid = threadIdx.x;
  const int qr = tid >> 2;
  const int kg = tid & 3;
  const int qtile = blockIdx.x;          // 0..31
  const int bh = blockIdx.y;             // 0..63
  const int b = bh >> 5, h = bh & 31;
  const int rowbase = b * 2048;
  const int q_l = qtile * 64 + qr;

  // q row -> 64 fp32 regs
  float q[64];
  {
    const uint4* qp4 = (const uint4*)(QKV + (size_t)(rowbase + q_l) * 6144 + h * 64);
    #pragma unroll
    for (int j = 0; j < 8; ++j) {
      uint4 u = qp4[j];
      q[j*8+0] = bf2f(u.x); q[j*8+1] = bf2f(u.x >> 16);
      q[j*8+2] = bf2f(u.y); q[j*8+3] = bf2f(u.y >> 16);
      q[j*8+4] = bf2f(u.z); q[j*8+5] = bf2f(u.z >> 16);
      q[j*8+6] = bf2f(u.w); q[j*8+7] = bf2f(u.w >> 16);
    }
  }
  float o[16];
  #pragma unroll
  for (int d = 0; d < 16; ++d) o[d] = 0.f;
  float m = -__builtin_inff();
  float lsum = 0.f;

  for (int kt = 0; kt < 32; ++kt) {
    __syncthreads();   // prior-iter P/V reads done before overwrite
    // stage K,V tile row qr, cols kg*16..+16
    {
      const unsigned short* kp = QKV + (size_t)(rowbase + kt * 64 + qr) * 6144
                                 + 2048 + h * 64 + kg * 16;
      const uint4* kp4 = (const uint4*)kp;
      const uint4* vp4 = (const uint4*)(kp + 2048);
      uint4 ka = kp4[0], kb = kp4[1];
      uint4 va = vp4[0], vb = vp4[1];
      float kf[16], vf[16];
      kf[0]=bf2f(ka.x); kf[1]=bf2f(ka.x>>16); kf[2]=bf2f(ka.y); kf[3]=bf2f(ka.y>>16);
      kf[4]=bf2f(ka.z); kf[5]=bf2f(ka.z>>16); kf[6]=bf2f(ka.w); kf[7]=bf2f(ka.w>>16);
      kf[8]=bf2f(kb.x); kf[9]=bf2f(kb.x>>16); kf[10]=bf2f(kb.y); kf[11]=bf2f(kb.y>>16);
      kf[12]=bf2f(kb.z); kf[13]=bf2f(kb.z>>16); kf[14]=bf2f(kb.w); kf[15]=bf2f(kb.w>>16);
      vf[0]=bf2f(va.x); vf[1]=bf2f(va.x>>16); vf[2]=bf2f(va.y); vf[3]=bf2f(va.y>>16);
      vf[4]=bf2f(va.z); vf[5]=bf2f(va.z>>16); vf[6]=bf2f(va.w); vf[7]=bf2f(va.w>>16);
      vf[8]=bf2f(vb.x); vf[9]=bf2f(vb.x>>16); vf[10]=bf2f(vb.y); vf[11]=bf2f(vb.y>>16);
      vf[12]=bf2f(vb.z); vf[13]=bf2f(vb.z>>16); vf[14]=bf2f(vb.w); vf[15]=bf2f(vb.w>>16);
      #pragma unroll
      for (int c4 = 0; c4 < 4; ++c4) {
        *(float4*)&Ks[qr * 68 + kg * 16 + c4 * 4] =
            make_float4(kf[c4*4], kf[c4*4+1], kf[c4*4+2], kf[c4*4+3]);
        *(float4*)&Vs[qr * 68 + kg * 16 + c4 * 4] =
            make_float4(vf[c4*4], vf[c4*4+1], vf[c4*4+2], vf[c4*4+3]);
      }
    }
    __syncthreads();

    // S: 16 dots, kpos = kg + 4*kk
    float s[16];
    #pragma unroll
    for (int kk = 0; kk < 16; ++kk) {
      const float* kr = &Ks[(kg + kk * 4) * 68];
      float a = 0.f;
      #pragma unroll
      for (int d4 = 0; d4 < 16; ++d4) {
        float4 kv = *(const float4*)&kr[d4 * 4];
        a += q[d4*4+0]*kv.x + q[d4*4+1]*kv.y + q[d4*4+2]*kv.z + q[d4*4+3]*kv.w;
      }
      s[kk] = a * 0.125f;   // 1/sqrt(64)
    }
    float tmax = s[0];
    #pragma unroll
    for (int kk = 1; kk < 16; ++kk) tmax = fmaxf(tmax, s[kk]);
    tmax = fmaxf(tmax, __shfl_xor(tmax, 1));
    tmax = fmaxf(tmax, __shfl_xor(tmax, 2));
    const float mnew = fmaxf(m, tmax);
    const float alpha = __expf(m - mnew);

    __syncthreads();   // all waves done reading Ks as K; reuse as P
    float psum = 0.f;
    #pragma unroll
    for (int kk = 0; kk < 16; ++kk) {
      const float p = __expf(s[kk] - mnew);
      psum += p;
      Ks[qr * 68 + kg + kk * 4] = p;   // P[qr][kpos]; read back by same wave only
    }
    psum += __shfl_xor(psum, 1);
    psum += __shfl_xor(psum, 2);
    lsum = lsum * alpha + psum;
    m = mnew;
    #pragma unroll
    for (int d = 0; d < 16; ++d) o[d] *= alpha;

    // O += P @ V   (own dims kg*16..+16)
    for (int kp2 = 0; kp2 < 64; ++kp2) {
      const float p = Ks[qr * 68 + kp2];
      const float* vr = &Vs[kp2 * 68 + kg * 16];
      #pragma unroll
      for (int d4 = 0; d4 < 4; ++d4) {
        float4 vv = *(const float4*)&vr[d4 * 4];
        o[d4*4+0] += p * vv.x; o[d4*4+1] += p * vv.y;
        o[d4*4+2] += p * vv.z; o[d4*4+3] += p * vv.w;
      }
    }
  }

  const float inv = 1.f / lsum;
  unsigned short* op = O + (size_t)(rowbase + q_l) * 2048 + h * 64 + kg * 16;
  #pragma unroll
  for (int d = 0; d < 16; ++d) op[d] = f2bf(o[d] * inv);
}

// ---------------------------------------------------------------------------
// launch
// ---------------------------------------------------------------------------
extern "C" void kernel_launch(void* const* d_in, const int* in_sizes, int n_in,
                              void* d_out, int out_size, void* d_ws, size_t ws_size,
                              hipStream_t stream) {
  (void)in_sizes; (void)n_in; (void)out_size; (void)ws_size;
  const float* x     = (const float*)d_in[0];   // [2,2048,2048]
  const float* cond  = (const float*)d_in[1];   // [2,2048]
  const float* rope  = (const float*)d_in[2];   // [2,2048,64]
  const float* w_ada = (const float*)d_in[3];   // [4096,2048]
  const float* w_qkv = (const float*)d_in[4];   // [6144,2048]
  const float* w_out = (const float*)d_in[5];   // [2048,2048]
  const float* qk_w  = (const float*)d_in[6];   // [64]
  float* out = (float*)d_out;                   // [2,2048,2048] fp32

  char* ws = (char*)d_ws;
  float*          ss  = (float*)ws;                       // 8192 f32   (32 KB)
  unsigned short* H   = (unsigned short*)(ws + 32768);    // 8.39M bf16 (16 MB), reused as O
  unsigned short* Wq  = H + 8388608;                      // 12.58M bf16 (24 MB)
  unsigned short* Wo  = Wq + 12582912;                    // 4.19M bf16 (8 MB)
  unsigned short* QKV = Wo + 4194304;                     // 25.17M bf16 (48 MB)

  ada_gemm_kernel<<<2048, 256, 0, stream>>>(cond, w_ada, ss);
  ada_rms_kernel<<<4096, 256, 0, stream>>>(x, ss, H);
  cast_kernel<<<12288, 256, 0, stream>>>(w_qkv, Wq, 3145728);
  cast_kernel<<<4096, 256, 0, stream>>>(w_out, Wo, 1048576);
  // qkv = H @ w_qkv^T  -> [4096, 6144] bf16
  gemm_bt_kernel<1><<<dim3(48, 32), 256, 0, stream>>>(H, Wq, (void*)QKV, 4096, 6144, 2048);
  qk_rope_kernel<<<32768, 256, 0, stream>>>(QKV, rope, qk_w);
  // attention -> O (reuses H buffer) [4096, 2048] bf16
  attn_kernel<<<dim3(32, 64), 256, 0, stream>>>(QKV, H);
  // out = O @ w_out^T -> fp32 d_out
  gemm_bt_kernel<0><<<dim3(16, 32), 256, 0, stream>>>(H, Wo, (void*)out, 4096, 2048, 2048);
}

// Round 2
// 502.151 us; speedup vs baseline: 3.5922x; 3.5922x over previous
//
#include <hip/hip_runtime.h>

// ---------------------------------------------------------------------------
// Attention_17703855194398: AdaRMSNorm -> QKV -> per-head RMS+RoPE -> SDPA -> out
// B=2, L=2048, D=2048, NH=32, HD=64, DC=2048
// R2: MFMA flash attention (no-max softmax, exp2 domain, permuted-k P packing,
//     V transposed+permuted in QKV-GEMM epilogue).
// ---------------------------------------------------------------------------

typedef __bf16 bf16x8 __attribute__((ext_vector_type(8)));
typedef float  f32x4  __attribute__((ext_vector_type(4)));
typedef float  f32x16 __attribute__((ext_vector_type(16)));

#define EPS_F32 1.1920929e-07f
// q prescale: (1/sqrt(64)) * log2(e)  -> scores land in exp2 domain
#define QSCALE 0.18033688011112042f

#if defined(__has_builtin)
#  if __has_builtin(__builtin_amdgcn_exp2f)
#    define EXP2F(x) __builtin_amdgcn_exp2f(x)
#  else
#    define EXP2F(x) __expf((x) * 0.6931471805599453f)
#  endif
#  if __has_builtin(__builtin_amdgcn_rcpf)
#    define RCPF(x) __builtin_amdgcn_rcpf(x)
#  else
#    define RCPF(x) (1.0f / (x))
#  endif
#else
#  define EXP2F(x) __expf((x) * 0.6931471805599453f)
#  define RCPF(x) (1.0f / (x))
#endif

__device__ __forceinline__ float bf2f(unsigned int u16) {
  union { unsigned int i; float f; } v; v.i = (u16 & 0xffffu) << 16; return v.f;
}
__device__ __forceinline__ unsigned short f2bf(float f) {
  union { float f; unsigned int i; } v; v.f = f;
  unsigned int r = v.i + 0x7fffu + ((v.i >> 16) & 1u);  // RNE
  return (unsigned short)(r >> 16);
}

// async global->LDS, 16B per lane (wave-uniform base + lane*16)
__device__ __forceinline__ void gload16(const void* g, void* l) {
  __builtin_amdgcn_global_load_lds(
      (const __attribute__((address_space(1))) unsigned int*)(unsigned long long)g,
      (__attribute__((address_space(3))) unsigned int*)(unsigned int)(unsigned long long)l,
      16, 0, 0);
}

// ---------------------------------------------------------------------------
// 1) ada GEMM: ss[b,j] = sum_k cond[b,k] * w_ada[j,k]
// ---------------------------------------------------------------------------
__global__ __launch_bounds__(256) void ada_gemm_kernel(
    const float* __restrict__ cond, const float* __restrict__ w_ada,
    float* __restrict__ ss)
{
  const int lane = threadIdx.x & 63;
  const int gw = blockIdx.x * 4 + (threadIdx.x >> 6);
  const int b = gw >> 12;
  const int j = gw & 4095;
  const float4* wr = (const float4*)(w_ada + j * 2048);
  const float4* cr = (const float4*)(cond + b * 2048);
  float acc = 0.f;
  #pragma unroll
  for (int k4 = 0; k4 < 8; ++k4) {
    float4 w = wr[lane + k4 * 64];
    float4 c = cr[lane + k4 * 64];
    acc += w.x * c.x + w.y * c.y + w.z * c.z + w.w * c.w;
  }
  #pragma unroll
  for (int off = 1; off < 64; off <<= 1) acc += __shfl_xor(acc, off);
  if (lane == 0) ss[b * 4096 + j] = acc;
}

// ---------------------------------------------------------------------------
// 2) AdaRMSNorm: h = rms_norm(x)*(1+scale) + shift, write bf16
// ---------------------------------------------------------------------------
__global__ __launch_bounds__(256) void ada_rms_kernel(
    const float* __restrict__ x, const float* __restrict__ ss,
    unsigned short* __restrict__ H)
{
  const int row = blockIdx.x;
  const int b = row >> 11;
  const int tid = threadIdx.x;
  const int lane = tid & 63, wave = tid >> 6;
  const float* xr = x + (size_t)row * 2048;
  float4 v0 = ((const float4*)xr)[tid * 2];
  float4 v1 = ((const float4*)xr)[tid * 2 + 1];
  float ssq = v0.x*v0.x + v0.y*v0.y + v0.z*v0.z + v0.w*v0.w
            + v1.x*v1.x + v1.y*v1.y + v1.z*v1.z + v1.w*v1.w;
  #pragma unroll
  for (int off = 1; off < 64; off <<= 1) ssq += __shfl_xor(ssq, off);
  __shared__ float red[4];
  if (lane == 0) red[wave] = ssq;
  __syncthreads();
  const float tot = red[0] + red[1] + red[2] + red[3];
  const float r = rsqrtf(tot * (1.f / 2048.f) + EPS_F32);
  const int c0 = tid * 8;
  const float* sh = ss + b * 4096;
  float xv[8] = {v0.x, v0.y, v0.z, v0.w, v1.x, v1.y, v1.z, v1.w};
  unsigned int pk[4];
  #pragma unroll
  for (int p = 0; p < 4; ++p) {
    const int c = c0 + p * 2;
    float h0 = xv[p*2+0] * r * (1.f + sh[2048 + c])     + sh[c];
    float h1 = xv[p*2+1] * r * (1.f + sh[2048 + c + 1]) + sh[c + 1];
    pk[p] = (unsigned int)f2bf(h0) | ((unsigned int)f2bf(h1) << 16);
  }
  *(uint4*)&H[(size_t)row * 2048 + c0] = make_uint4(pk[0], pk[1], pk[2], pk[3]);
}

// ---------------------------------------------------------------------------
// 3) fp32 -> bf16 weight cast
// ---------------------------------------------------------------------------
__global__ __launch_bounds__(256) void cast_kernel(
    const float* __restrict__ src, unsigned short* __restrict__ dst, int n4)
{
  const int i = blockIdx.x * 256 + threadIdx.x;
  if (i >= n4) return;
  float4 v = ((const float4*)src)[i];
  unsigned int p0 = (unsigned int)f2bf(v.x) | ((unsigned int)f2bf(v.y) << 16);
  unsigned int p1 = (unsigned int)f2bf(v.z) | ((unsigned int)f2bf(v.w) << 16);
  *(uint2*)&dst[(size_t)i * 4] = make_uint2(p0, p1);
}

// ---------------------------------------------------------------------------
// 4) bf16 MFMA GEMM, C[M,N] = A[M,K] @ Bw[N,K]^T (m97 structure).
//    MODE 0: f32 C.  MODE 2: bf16 C, and cols >= 4096 (the V third of QKV)
//    are written to vt[bh][d][k] TRANSPOSED with the per-64-tile key
//    permutation p = (l&15)*4 + ((l>>4)&3) that matches attn's P packing.
// ---------------------------------------------------------------------------
template <int MODE>
__global__ __launch_bounds__(256) void gemm_bt_kernel(
    const unsigned short* __restrict__ A,   // [M,K] bf16
    const unsigned short* __restrict__ Bw,  // [N,K] bf16
    void* __restrict__ Cv,                  // [M,N] bf16 or f32
    unsigned short* __restrict__ vt,        // MODE 2 only
    int M, int N, int K)
{
  __shared__ unsigned short As[128 * 32];
  __shared__ unsigned short Bs[128 * 32];
  const int tid  = threadIdx.x;
  const int lane = tid & 63;
  const int wave = tid >> 6;
  const int wm = (wave >> 1) * 64;
  const int wn = (wave & 1) * 64;
  const int bm = blockIdx.y * 128;
  const int bn = blockIdx.x * 128;

  f32x4 acc[4][4] = {};

  const int sm = tid >> 2;
  const int sk = (tid & 3) * 8;
  const unsigned short* Ap  = A  + (size_t)(bm + sm) * K + sk;
  const unsigned short* Ap2 = Ap + (size_t)64 * K;
  const unsigned short* Bp  = Bw + (size_t)(bn + sm) * K + sk;
  const unsigned short* Bp2 = Bp + (size_t)64 * K;
  unsigned short* lA  = &As[tid * 8];
  unsigned short* lA2 = &As[tid * 8 + 2048];
  unsigned short* lB  = &Bs[tid * 8];
  unsigned short* lB2 = &Bs[tid * 8 + 2048];

  const int fr = lane & 15;
  const int fk = (lane >> 4) * 8;

  for (int k0 = 0; k0 < K; k0 += 32) {
    __syncthreads();
    gload16(Ap  + k0, lA);
    gload16(Ap2 + k0, lA2);
    gload16(Bp  + k0, lB);
    gload16(Bp2 + k0, lB2);
    __syncthreads();

    bf16x8 af[4], bfr[4];
    #pragma unroll
    for (int i = 0; i < 4; ++i)
      af[i] = *(const bf16x8*)&As[(wm + i * 16 + fr) * 32 + fk];
    #pragma unroll
    for (int j = 0; j < 4; ++j)
      bfr[j] = *(const bf16x8*)&Bs[(wn + j * 16 + fr) * 32 + fk];
    #pragma unroll
    for (int i = 0; i < 4; ++i)
      #pragma unroll
      for (int j = 0; j < 4; ++j)
        acc[i][j] = __builtin_amdgcn_mfma_f32_16x16x32_bf16(af[i], bfr[j], acc[i][j], 0, 0, 0);
  }

  const int cr = (lane >> 4) * 4;
  const int cc = lane & 15;
  if (MODE == 2 && bn >= 4096) {
    // V third -> transposed+permuted Vt[((b*32+h)*64+d)][2048]
    #pragma unroll
    for (int i = 0; i < 4; ++i)
      #pragma unroll
      for (int j = 0; j < 4; ++j)
        #pragma unroll
        for (int r = 0; r < 4; ++r) {
          const int m  = bm + wm + i * 16 + cr + r;
          const int dg = bn + wn + j * 16 + cc - 4096;
          const int l  = m & 2047;
          const size_t dst = ((size_t)((m >> 11) * 32 + (dg >> 6)) * 64 + (dg & 63)) * 2048
                           + (l >> 6) * 64 + (l & 15) * 4 + ((l >> 4) & 3);
          vt[dst] = f2bf(acc[i][j][r]);
        }
  } else {
    #pragma unroll
    for (int i = 0; i < 4; ++i)
      #pragma unroll
      for (int j = 0; j < 4; ++j)
        #pragma unroll
        for (int r = 0; r < 4; ++r) {
          const int row = bm + wm + i * 16 + cr + r;
          const int col = bn + wn + j * 16 + cc;
          if (MODE != 0)
            ((unsigned short*)Cv)[(size_t)row * N + col] = f2bf(acc[i][j][r]);
          else
            ((float*)Cv)[(size_t)row * N + col] = acc[i][j][r];
        }
  }
}

// ---------------------------------------------------------------------------
// 5) per-head RMSNorm(qk_w) + RoPE on q,k in place; q additionally scaled by
//    QSCALE = 0.125*log2(e) so attention scores are in exp2 domain.
// ---------------------------------------------------------------------------
__global__ __launch_bounds__(256) void qk_rope_kernel(
    unsigned short* __restrict__ QKV, const float* __restrict__ rope,
    const float* __restrict__ qk_w)
{
  const int lane = threadIdx.x & 63;
  const int gid = blockIdx.x * 4 + (threadIdx.x >> 6);
  const int l = gid & 2047;
  const int h = (gid >> 11) & 31;
  const int b = gid >> 16;
  const int base = (b * 2048 + l) * 6144 + h * 64 + lane;
  const float r0 = rope[l * 64 + lane];
  const float r1 = rope[131072 + l * 64 + lane];
  const float w  = qk_w[lane];
  #pragma unroll
  for (int t = 0; t < 2; ++t) {        // t=0: q, t=1: k
    const int idx = base + 2048 * t;
    const float v = bf2f(QKV[idx]);
    float sq = v * v;
    #pragma unroll
    for (int off = 1; off < 64; off <<= 1) sq += __shfl_xor(sq, off);
    const float vn = v * rsqrtf(sq * (1.f / 64.f) + EPS_F32) * w;
    const float vp = __shfl_xor(vn, 1);
    const float vh = (lane & 1) ? vp : -vp;
    const float scale = (t == 0) ? QSCALE : 1.0f;
    QKV[idx] = f2bf((vn * r0 + vh * r1) * scale);
  }
}

// ---------------------------------------------------------------------------
// 6) MFMA flash attention, no-max softmax (scores bounded ~|13|, fp32 safe).
//    Block: (b,h) x 128-q-tile; wave owns 32 q rows (2x 16-row S tiles).
//    k-tile = 64. S via 16x16x32 (A=Q regs, B=K LDS). P packed with permuted
//    key order p=c*4+kj -> ds_write_b64. PV + row-sums via 32x32x16
//    (A=P LDS, B=Vt LDS, pre-permuted in global).
// ---------------------------------------------------------------------------
__global__ __launch_bounds__(256) void attn_mfma_kernel(
    const unsigned short* __restrict__ QKV,  // [4096][6144] (q,k roped)
    const unsigned short* __restrict__ Vt,   // [64 bh][64 d][2048 k-perm]
    unsigned short* __restrict__ O)          // [4096][2048]
{
  __shared__ unsigned short Ks[64 * 72];
  __shared__ unsigned short Vs[64 * 72];
  __shared__ unsigned short Ps[4 * 32 * 68];
  const int tid  = threadIdx.x;
  const int lane = tid & 63;
  const int wave = tid >> 6;
  const int qt = blockIdx.x;               // 0..15
  const int bh = blockIdx.y;               // 0..63
  const int b = bh >> 5, h = bh & 31;
  const int rowbase = b << 11;
  const int qbase = qt * 128 + wave * 32;  // q row base (within L)

  const int m16  = lane & 15;
  const int quad = lane >> 4;
  const int m32  = lane & 31;
  const int hl   = lane >> 5;

  // Q fragments (already scaled by QSCALE in rope kernel)
  bf16x8 qf[2][2];
  #pragma unroll
  for (int qi = 0; qi < 2; ++qi)
    #pragma unroll
    for (int ch = 0; ch < 2; ++ch)
      qf[qi][ch] = *(const bf16x8*)&QKV[(size_t)(rowbase + qbase + qi * 16 + m16) * 6144
                                        + h * 64 + ch * 32 + quad * 8];

  const int sr = tid >> 2;            // staging row 0..63
  const int sc = (tid & 3) * 16;      // staging col (shorts)
  const unsigned short* Kg = QKV + (size_t)(rowbase + sr) * 6144 + 2048 + h * 64 + sc;
  const unsigned short* Vg = Vt + (size_t)(bh * 64 + sr) * 2048 + sc;

  f32x16 accO[2] = {};
  float part[2][4] = {{0.f, 0.f, 0.f, 0.f}, {0.f, 0.f, 0.f, 0.f}};
  unsigned short* Pw = &Ps[(wave * 32) * 68];

  for (int kt = 0; kt < 32; ++kt) {
    __syncthreads();                  // prior-iter Ks/Vs reads done
    {
      const uint4* kp = (const uint4*)(Kg + (size_t)kt * 64 * 6144);
      const uint4* vp = (const uint4*)(Vg + kt * 64);
      uint4 k0 = kp[0], k1 = kp[1];
      uint4 v0 = vp[0], v1 = vp[1];
      *(uint4*)&Ks[sr * 72 + sc]     = k0;
      *(uint4*)&Ks[sr * 72 + sc + 8] = k1;
      *(uint4*)&Vs[sr * 72 + sc]     = v0;
      *(uint4*)&Vs[sr * 72 + sc + 8] = v1;
    }
    __syncthreads();

    // S (16x16x32), exp2, pack P with permuted key index p = c*4 + kj
    unsigned int pk[2][4][2];
    #pragma unroll
    for (int kj = 0; kj < 4; ++kj) {
      bf16x8 kf0 = *(const bf16x8*)&Ks[(kj * 16 + m16) * 72 + quad * 8];
      bf16x8 kf1 = *(const bf16x8*)&Ks[(kj * 16 + m16) * 72 + 32 + quad * 8];
      #pragma unroll
      for (int qi = 0; qi < 2; ++qi) {
        f32x4 acc = {};
        acc = __builtin_amdgcn_mfma_f32_16x16x32_bf16(qf[qi][0], kf0, acc, 0, 0, 0);
        acc = __builtin_amdgcn_mfma_f32_16x16x32_bf16(qf[qi][1], kf1, acc, 0, 0, 0);
        #pragma unroll
        for (int r = 0; r < 4; ++r) {
          float p = EXP2F(acc[r]);
          part[qi][r] += p;
          unsigned int pb = f2bf(p);
          if (kj == 0)      pk[qi][r][0]  = pb;
          else if (kj == 1) pk[qi][r][0] |= pb << 16;
          else if (kj == 2) pk[qi][r][1]  = pb;
          else              pk[qi][r][1] |= pb << 16;
        }
      }
    }
    #pragma unroll
    for (int qi = 0; qi < 2; ++qi)
      #pragma unroll
      for (int r = 0; r < 4; ++r)
        *(uint2*)&Pw[(qi * 16 + quad * 4 + r) * 68 + m16 * 4] =
            make_uint2(pk[qi][r][0], pk[qi][r][1]);
    // wave-private P: RAW handled by lgkmcnt, no barrier needed

    // PV (32x32x16): O[32q][64d] over permuted k
    #pragma unroll
    for (int ch = 0; ch < 4; ++ch) {
      bf16x8 pa = *(const bf16x8*)&Pw[m32 * 68 + ch * 16 + hl * 8];
      #pragma unroll
      for (int dt = 0; dt < 2; ++dt) {
        bf16x8 vb = *(const bf16x8*)&Vs[(dt * 32 + m32) * 72 + ch * 16 + hl * 8];
        accO[dt] = __builtin_amdgcn_mfma_f32_32x32x16_bf16(pa, vb, accO[dt], 0, 0, 0);
      }
    }
  }

  // lsum: reduce per-lane partials across the 16 c-lanes
  #pragma unroll
  for (int qi = 0; qi < 2; ++qi)
    #pragma unroll
    for (int r = 0; r < 4; ++r)
      #pragma unroll
      for (int off = 1; off < 16; off <<= 1)
        part[qi][r] += __shfl_xor(part[qi][r], off);

  // epilogue: gather row-sum into 32x32 C-layout rows, divide, store
  #pragma unroll
  for (int reg = 0; reg < 16; ++reg) {
    const int r  = reg & 3;
    const int qi = reg >> 3;                         // uniform per reg
    const int qsrc = ((2 * (reg >> 2) + hl) & 3) * 16 + m16;
    const float rs = __shfl(part[qi][r], qsrc);
    const float inv = RCPF(rs);
    const int rho = (reg & 3) + 8 * (reg >> 2) + 4 * hl;   // q row within wave tile
    const size_t base = (size_t)(rowbase + qbase + rho) * 2048 + h * 64;
    O[base + m32]      = f2bf(accO[0][reg] * inv);
    O[base + 32 + m32] = f2bf(accO[1][reg] * inv);
  }
}

// ---------------------------------------------------------------------------
// launch
// ---------------------------------------------------------------------------
extern "C" void kernel_launch(void* const* d_in, const int* in_sizes, int n_in,
                              void* d_out, int out_size, void* d_ws, size_t ws_size,
                              hipStream_t stream) {
  (void)in_sizes; (void)n_in; (void)out_size; (void)ws_size;
  const float* x     = (const float*)d_in[0];
  const float* cond  = (const float*)d_in[1];
  const float* rope  = (const float*)d_in[2];
  const float* w_ada = (const float*)d_in[3];
  const float* w_qkv = (const float*)d_in[4];
  const float* w_out = (const float*)d_in[5];
  const float* qk_w  = (const float*)d_in[6];
  float* out = (float*)d_out;

  char* ws = (char*)d_ws;
  float*          ss   = (float*)ws;                       // 32 KB
  unsigned short* H    = (unsigned short*)(ws + 32768);    // 16 MB, reused as O
  unsigned short* Wq   = H + 8388608;                      // 24 MB
  unsigned short* Wo   = Wq + 12582912;                    // 8 MB
  unsigned short* QKV  = Wo + 4194304;                     // 48 MB (q,k used)
  unsigned short* Vt_g = QKV + 25165824;                   // 16 MB

  ada_gemm_kernel<<<2048, 256, 0, stream>>>(cond, w_ada, ss);
  ada_rms_kernel<<<4096, 256, 0, stream>>>(x, ss, H);
  cast_kernel<<<12288, 256, 0, stream>>>(w_qkv, Wq, 3145728);
  cast_kernel<<<4096, 256, 0, stream>>>(w_out, Wo, 1048576);
  // qkv = H @ w_qkv^T ; q,k -> QKV, v -> Vt_g (transposed + k-permuted)
  gemm_bt_kernel<2><<<dim3(48, 32), 256, 0, stream>>>(H, Wq, (void*)QKV, Vt_g, 4096, 6144, 2048);
  qk_rope_kernel<<<32768, 256, 0, stream>>>(QKV, rope, qk_w);
  attn_mfma_kernel<<<dim3(16, 64), 256, 0, stream>>>(QKV, Vt_g, H);
  gemm_bt_kernel<0><<<dim3(16, 32), 256, 0, stream>>>(H, Wo, (void*)out, nullptr, 4096, 2048, 2048);
}

// Round 3
// 477.763 us; speedup vs baseline: 3.7756x; 1.0510x over previous
//
#include <hip/hip_runtime.h>

// ---------------------------------------------------------------------------
// Attention_17703855194398: AdaRMSNorm -> QKV -> per-head RMS+RoPE -> SDPA -> out
// B=2, L=2048, D=2048, NH=32, HD=64, DC=2048
// R3: attn = 64q/wave (256q/block), cheap bf16 pack, XCD-affine grid.
// ---------------------------------------------------------------------------

typedef __bf16 bf16x8 __attribute__((ext_vector_type(8)));
typedef float  f32x4  __attribute__((ext_vector_type(4)));
typedef float  f32x16 __attribute__((ext_vector_type(16)));

#define EPS_F32 1.1920929e-07f
// q prescale: (1/sqrt(64)) * log2(e)  -> scores land in exp2 domain
#define QSCALE 0.18033688011112042f

#if defined(__has_builtin)
#  if __has_builtin(__builtin_amdgcn_exp2f)
#    define EXP2F(x) __builtin_amdgcn_exp2f(x)
#  else
#    define EXP2F(x) __expf((x) * 0.6931471805599453f)
#  endif
#  if __has_builtin(__builtin_amdgcn_rcpf)
#    define RCPF(x) __builtin_amdgcn_rcpf(x)
#  else
#    define RCPF(x) (1.0f / (x))
#  endif
#else
#  define EXP2F(x) __expf((x) * 0.6931471805599453f)
#  define RCPF(x) (1.0f / (x))
#endif

__device__ __forceinline__ float bf2f(unsigned int u16) {
  union { unsigned int i; float f; } v; v.i = (u16 & 0xffffu) << 16; return v.f;
}
__device__ __forceinline__ unsigned short f2bf(float f) {
  union { float f; unsigned int i; } v; v.f = f;
  unsigned int r = v.i + 0x7fffu + ((v.i >> 16) & 1u);  // RNE
  return (unsigned short)(r >> 16);
}
// round-to-nearest (ties away) bf16 bits, cheap: 2 ops
__device__ __forceinline__ unsigned int f2bf_rn_u(float f) {
  union { float f; unsigned int i; } v; v.f = f;
  return v.i + 0x8000u;   // caller takes >>16 or &0xffff0000
}

// async global->LDS, 16B per lane (wave-uniform base + lane*16)
__device__ __forceinline__ void gload16(const void* g, void* l) {
  __builtin_amdgcn_global_load_lds(
      (const __attribute__((address_space(1))) unsigned int*)(unsigned long long)g,
      (__attribute__((address_space(3))) unsigned int*)(unsigned int)(unsigned long long)l,
      16, 0, 0);
}

// ---------------------------------------------------------------------------
// 1) ada GEMM: ss[b,j] = sum_k cond[b,k] * w_ada[j,k]
// ---------------------------------------------------------------------------
__global__ __launch_bounds__(256) void ada_gemm_kernel(
    const float* __restrict__ cond, const float* __restrict__ w_ada,
    float* __restrict__ ss)
{
  const int lane = threadIdx.x & 63;
  const int gw = blockIdx.x * 4 + (threadIdx.x >> 6);
  const int b = gw >> 12;
  const int j = gw & 4095;
  const float4* wr = (const float4*)(w_ada + j * 2048);
  const float4* cr = (const float4*)(cond + b * 2048);
  float acc = 0.f;
  #pragma unroll
  for (int k4 = 0; k4 < 8; ++k4) {
    float4 w = wr[lane + k4 * 64];
    float4 c = cr[lane + k4 * 64];
    acc += w.x * c.x + w.y * c.y + w.z * c.z + w.w * c.w;
  }
  #pragma unroll
  for (int off = 1; off < 64; off <<= 1) acc += __shfl_xor(acc, off);
  if (lane == 0) ss[b * 4096 + j] = acc;
}

// ---------------------------------------------------------------------------
// 2) AdaRMSNorm: h = rms_norm(x)*(1+scale) + shift, write bf16
// ---------------------------------------------------------------------------
__global__ __launch_bounds__(256) void ada_rms_kernel(
    const float* __restrict__ x, const float* __restrict__ ss,
    unsigned short* __restrict__ H)
{
  const int row = blockIdx.x;
  const int b = row >> 11;
  const int tid = threadIdx.x;
  const int lane = tid & 63, wave = tid >> 6;
  const float* xr = x + (size_t)row * 2048;
  float4 v0 = ((const float4*)xr)[tid * 2];
  float4 v1 = ((const float4*)xr)[tid * 2 + 1];
  float ssq = v0.x*v0.x + v0.y*v0.y + v0.z*v0.z + v0.w*v0.w
            + v1.x*v1.x + v1.y*v1.y + v1.z*v1.z + v1.w*v1.w;
  #pragma unroll
  for (int off = 1; off < 64; off <<= 1) ssq += __shfl_xor(ssq, off);
  __shared__ float red[4];
  if (lane == 0) red[wave] = ssq;
  __syncthreads();
  const float tot = red[0] + red[1] + red[2] + red[3];
  const float r = rsqrtf(tot * (1.f / 2048.f) + EPS_F32);
  const int c0 = tid * 8;
  const float* sh = ss + b * 4096;
  float xv[8] = {v0.x, v0.y, v0.z, v0.w, v1.x, v1.y, v1.z, v1.w};
  unsigned int pk[4];
  #pragma unroll
  for (int p = 0; p < 4; ++p) {
    const int c = c0 + p * 2;
    float h0 = xv[p*2+0] * r * (1.f + sh[2048 + c])     + sh[c];
    float h1 = xv[p*2+1] * r * (1.f + sh[2048 + c + 1]) + sh[c + 1];
    pk[p] = (unsigned int)f2bf(h0) | ((unsigned int)f2bf(h1) << 16);
  }
  *(uint4*)&H[(size_t)row * 2048 + c0] = make_uint4(pk[0], pk[1], pk[2], pk[3]);
}

// ---------------------------------------------------------------------------
// 3) fp32 -> bf16 weight cast, both weights in one launch.
//    dst is contiguous: [w_qkv bf16 : 12582912][w_out bf16 : 4194304]
// ---------------------------------------------------------------------------
__global__ __launch_bounds__(256) void cast2_kernel(
    const float* __restrict__ a,   // w_qkv, 3145728 float4
    const float* __restrict__ b,   // w_out, 1048576 float4
    unsigned short* __restrict__ dst)
{
  const int i = blockIdx.x * 256 + threadIdx.x;   // 0..4194303
  float4 v = (i < 3145728) ? ((const float4*)a)[i]
                           : ((const float4*)b)[i - 3145728];
  unsigned int p0 = (unsigned int)f2bf(v.x) | ((unsigned int)f2bf(v.y) << 16);
  unsigned int p1 = (unsigned int)f2bf(v.z) | ((unsigned int)f2bf(v.w) << 16);
  *(uint2*)&dst[(size_t)i * 4] = make_uint2(p0, p1);
}

// ---------------------------------------------------------------------------
// 4) bf16 MFMA GEMM, C[M,N] = A[M,K] @ Bw[N,K]^T (m97 structure).
//    MODE 0: f32 C.  MODE 2: bf16 C; cols >= 4096 (V third of QKV) go to
//    vt[bh][d][k] transposed with per-64-tile key permutation p=(l&15)*4+((l>>4)&3).
// ---------------------------------------------------------------------------
template <int MODE>
__global__ __launch_bounds__(256) void gemm_bt_kernel(
    const unsigned short* __restrict__ A,   // [M,K] bf16
    const unsigned short* __restrict__ Bw,  // [N,K] bf16
    void* __restrict__ Cv,                  // [M,N] bf16 or f32
    unsigned short* __restrict__ vt,        // MODE 2 only
    int M, int N, int K)
{
  __shared__ unsigned short As[128 * 32];
  __shared__ unsigned short Bs[128 * 32];
  const int tid  = threadIdx.x;
  const int lane = tid & 63;
  const int wave = tid >> 6;
  const int wm = (wave >> 1) * 64;
  const int wn = (wave & 1) * 64;
  const int bm = blockIdx.y * 128;
  const int bn = blockIdx.x * 128;

  f32x4 acc[4][4] = {};

  const int sm = tid >> 2;
  const int sk = (tid & 3) * 8;
  const unsigned short* Ap  = A  + (size_t)(bm + sm) * K + sk;
  const unsigned short* Ap2 = Ap + (size_t)64 * K;
  const unsigned short* Bp  = Bw + (size_t)(bn + sm) * K + sk;
  const unsigned short* Bp2 = Bp + (size_t)64 * K;
  unsigned short* lA  = &As[tid * 8];
  unsigned short* lA2 = &As[tid * 8 + 2048];
  unsigned short* lB  = &Bs[tid * 8];
  unsigned short* lB2 = &Bs[tid * 8 + 2048];

  const int fr = lane & 15;
  const int fk = (lane >> 4) * 8;

  for (int k0 = 0; k0 < K; k0 += 32) {
    __syncthreads();
    gload16(Ap  + k0, lA);
    gload16(Ap2 + k0, lA2);
    gload16(Bp  + k0, lB);
    gload16(Bp2 + k0, lB2);
    __syncthreads();

    bf16x8 af[4], bfr[4];
    #pragma unroll
    for (int i = 0; i < 4; ++i)
      af[i] = *(const bf16x8*)&As[(wm + i * 16 + fr) * 32 + fk];
    #pragma unroll
    for (int j = 0; j < 4; ++j)
      bfr[j] = *(const bf16x8*)&Bs[(wn + j * 16 + fr) * 32 + fk];
    #pragma unroll
    for (int i = 0; i < 4; ++i)
      #pragma unroll
      for (int j = 0; j < 4; ++j)
        acc[i][j] = __builtin_amdgcn_mfma_f32_16x16x32_bf16(af[i], bfr[j], acc[i][j], 0, 0, 0);
  }

  const int cr = (lane >> 4) * 4;
  const int cc = lane & 15;
  if (MODE == 2 && bn >= 4096) {
    #pragma unroll
    for (int i = 0; i < 4; ++i)
      #pragma unroll
      for (int j = 0; j < 4; ++j)
        #pragma unroll
        for (int r = 0; r < 4; ++r) {
          const int m  = bm + wm + i * 16 + cr + r;
          const int dg = bn + wn + j * 16 + cc - 4096;
          const int l  = m & 2047;
          const size_t dst = ((size_t)((m >> 11) * 32 + (dg >> 6)) * 64 + (dg & 63)) * 2048
                           + (l >> 6) * 64 + (l & 15) * 4 + ((l >> 4) & 3);
          vt[dst] = f2bf(acc[i][j][r]);
        }
  } else {
    #pragma unroll
    for (int i = 0; i < 4; ++i)
      #pragma unroll
      for (int j = 0; j < 4; ++j)
        #pragma unroll
        for (int r = 0; r < 4; ++r) {
          const int row = bm + wm + i * 16 + cr + r;
          const int col = bn + wn + j * 16 + cc;
          if (MODE != 0)
            ((unsigned short*)Cv)[(size_t)row * N + col] = f2bf(acc[i][j][r]);
          else
            ((float*)Cv)[(size_t)row * N + col] = acc[i][j][r];
        }
  }
}

// ---------------------------------------------------------------------------
// 5) per-head RMSNorm(qk_w) + RoPE on q,k in place; q scaled by QSCALE.
// ---------------------------------------------------------------------------
__global__ __launch_bounds__(256) void qk_rope_kernel(
    unsigned short* __restrict__ QKV, const float* __restrict__ rope,
    const float* __restrict__ qk_w)
{
  const int lane = threadIdx.x & 63;
  const int gid = blockIdx.x * 4 + (threadIdx.x >> 6);
  const int l = gid & 2047;
  const int h = (gid >> 11) & 31;
  const int b = gid >> 16;
  const int base = (b * 2048 + l) * 6144 + h * 64 + lane;
  const float r0 = rope[l * 64 + lane];
  const float r1 = rope[131072 + l * 64 + lane];
  const float w  = qk_w[lane];
  #pragma unroll
  for (int t = 0; t < 2; ++t) {        // t=0: q, t=1: k
    const int idx = base + 2048 * t;
    const float v = bf2f(QKV[idx]);
    float sq = v * v;
    #pragma unroll
    for (int off = 1; off < 64; off <<= 1) sq += __shfl_xor(sq, off);
    const float vn = v * rsqrtf(sq * (1.f / 64.f) + EPS_F32) * w;
    const float vp = __shfl_xor(vn, 1);
    const float vh = (lane & 1) ? vp : -vp;
    const float scale = (t == 0) ? QSCALE : 1.0f;
    QKV[idx] = f2bf((vn * r0 + vh * r1) * scale);
  }
}

// ---------------------------------------------------------------------------
// 6) MFMA flash attention (no-max softmax). 64q/wave, 256q/block, k-tile 64.
//    S via 16x16x32 (A=Q regs, B=K LDS), P packed w/ permuted key p=c*4+kj,
//    PV via 32x32x16 (A=P LDS, B=Vt LDS, pre-permuted in global).
//    1-D grid, bh = blk&63 (XCD-affine: all q-tiles of a head on one XCD).
// ---------------------------------------------------------------------------
__global__ __launch_bounds__(256, 2) void attn_mfma_kernel(
    const unsigned short* __restrict__ QKV,  // [4096][6144] (q,k roped)
    const unsigned short* __restrict__ Vt,   // [64 bh][64 d][2048 k-perm]
    unsigned short* __restrict__ O)          // [4096][2048]
{
  __shared__ unsigned short Ks[64 * 72];
  __shared__ unsigned short Vs[64 * 72];
  __shared__ unsigned short Ps[4 * 64 * 68];
  const int tid  = threadIdx.x;
  const int lane = tid & 63;
  const int wave = tid >> 6;
  const int blk = blockIdx.x;              // 0..511
  const int bh = blk & 63;                 // blk%8 == bh%8 -> XCD-affine
  const int qt = blk >> 6;                 // 0..7
  const int b = bh >> 5, h = bh & 31;
  const int rowbase = b << 11;
  const int qbase = qt * 256 + wave * 64;  // 64 q rows per wave

  const int m16  = lane & 15;
  const int quad = lane >> 4;
  const int m32  = lane & 31;
  const int hl   = lane >> 5;

  // Q fragments (already scaled by QSCALE in rope kernel): 4 x 16-row tiles
  bf16x8 qf[4][2];
  #pragma unroll
  for (int qi = 0; qi < 4; ++qi)
    #pragma unroll
    for (int ch = 0; ch < 2; ++ch)
      qf[qi][ch] = *(const bf16x8*)&QKV[(size_t)(rowbase + qbase + qi * 16 + m16) * 6144
                                        + h * 64 + ch * 32 + quad * 8];

  const int sr = tid >> 2;            // staging row 0..63
  const int sc = (tid & 3) * 16;      // staging col (shorts)
  const unsigned short* Kg = QKV + (size_t)(rowbase + sr) * 6144 + 2048 + h * 64 + sc;
  const unsigned short* Vg = Vt + (size_t)(bh * 64 + sr) * 2048 + sc;

  f32x16 accO[2][2] = {};                 // [q-subtile 32][d-tile 32]
  float part[4][4] = {};                  // per-16-row-tile row sums
  unsigned short* Pw = &Ps[(wave * 64) * 68];

  for (int kt = 0; kt < 32; ++kt) {
    __syncthreads();
    {
      const uint4* kp = (const uint4*)(Kg + (size_t)kt * 64 * 6144);
      const uint4* vp = (const uint4*)(Vg + kt * 64);
      uint4 k0 = kp[0], k1 = kp[1];
      uint4 v0 = vp[0], v1 = vp[1];
      *(uint4*)&Ks[sr * 72 + sc]     = k0;
      *(uint4*)&Ks[sr * 72 + sc + 8] = k1;
      *(uint4*)&Vs[sr * 72 + sc]     = v0;
      *(uint4*)&Vs[sr * 72 + sc + 8] = v1;
    }
    __syncthreads();

    // S (16x16x32) -> exp2 -> pack P (key perm p = c*4 + kj)
    unsigned int pk[4][4][2];
    #pragma unroll
    for (int kj = 0; kj < 4; ++kj) {
      bf16x8 kf0 = *(const bf16x8*)&Ks[(kj * 16 + m16) * 72 + quad * 8];
      bf16x8 kf1 = *(const bf16x8*)&Ks[(kj * 16 + m16) * 72 + 32 + quad * 8];
      #pragma unroll
      for (int qi = 0; qi < 4; ++qi) {
        f32x4 acc = {};
        acc = __builtin_amdgcn_mfma_f32_16x16x32_bf16(qf[qi][0], kf0, acc, 0, 0, 0);
        acc = __builtin_amdgcn_mfma_f32_16x16x32_bf16(qf[qi][1], kf1, acc, 0, 0, 0);
        #pragma unroll
        for (int r = 0; r < 4; ++r) {
          float p = EXP2F(acc[r]);
          part[qi][r] += p;
          unsigned int pb = f2bf_rn_u(p);
          if (kj == 0)      pk[qi][r][0]  = pb >> 16;
          else if (kj == 1) pk[qi][r][0] |= pb & 0xffff0000u;
          else if (kj == 2) pk[qi][r][1]  = pb >> 16;
          else              pk[qi][r][1] |= pb & 0xffff0000u;
        }
      }
    }
    #pragma unroll
    for (int qi = 0; qi < 4; ++qi)
      #pragma unroll
      for (int r = 0; r < 4; ++r)
        *(uint2*)&Pw[(qi * 16 + quad * 4 + r) * 68 + m16 * 4] =
            make_uint2(pk[qi][r][0], pk[qi][r][1]);
    // wave-private P region: RAW covered by lgkmcnt, no barrier

    // PV (32x32x16): accO[qs][dt], vb reused across qs
    #pragma unroll
    for (int ch = 0; ch < 4; ++ch) {
      bf16x8 pa0 = *(const bf16x8*)&Pw[m32 * 68 + ch * 16 + hl * 8];
      bf16x8 pa1 = *(const bf16x8*)&Pw[(32 + m32) * 68 + ch * 16 + hl * 8];
      bf16x8 vb0 = *(const bf16x8*)&Vs[m32 * 72 + ch * 16 + hl * 8];
      bf16x8 vb1 = *(const bf16x8*)&Vs[(32 + m32) * 72 + ch * 16 + hl * 8];
      accO[0][0] = __builtin_amdgcn_mfma_f32_32x32x16_bf16(pa0, vb0, accO[0][0], 0, 0, 0);
      accO[0][1] = __builtin_amdgcn_mfma_f32_32x32x16_bf16(pa0, vb1, accO[0][1], 0, 0, 0);
      accO[1][0] = __builtin_amdgcn_mfma_f32_32x32x16_bf16(pa1, vb0, accO[1][0], 0, 0, 0);
      accO[1][1] = __builtin_amdgcn_mfma_f32_32x32x16_bf16(pa1, vb1, accO[1][1], 0, 0, 0);
    }
  }

  // reduce row sums over the 16 n-lanes
  #pragma unroll
  for (int qi = 0; qi < 4; ++qi)
    #pragma unroll
    for (int r = 0; r < 4; ++r)
      #pragma unroll
      for (int off = 1; off < 16; off <<= 1)
        part[qi][r] += __shfl_xor(part[qi][r], off);

  // epilogue: per 32-row q-subtile, gather row sum, divide, store
  #pragma unroll
  for (int qs = 0; qs < 2; ++qs) {
    #pragma unroll
    for (int reg = 0; reg < 16; ++reg) {
      const int r = reg & 3;
      const int s = reg >> 2;
      const int qsrc = ((2 * s + hl) & 3) * 16 + m16;
      const float rs = __shfl(part[qs * 2 + (reg >> 3)][r], qsrc);
      const float inv = RCPF(rs);
      const int rho = r + 8 * s + 4 * hl;      // row in 32x32 C layout
      const size_t base = (size_t)(rowbase + qbase + qs * 32 + rho) * 2048 + h * 64;
      O[base + m32]      = f2bf(accO[qs][0][reg] * inv);
      O[base + 32 + m32] = f2bf(accO[qs][1][reg] * inv);
    }
  }
}

// ---------------------------------------------------------------------------
// launch
// ---------------------------------------------------------------------------
extern "C" void kernel_launch(void* const* d_in, const int* in_sizes, int n_in,
                              void* d_out, int out_size, void* d_ws, size_t ws_size,
                              hipStream_t stream) {
  (void)in_sizes; (void)n_in; (void)out_size; (void)ws_size;
  const float* x     = (const float*)d_in[0];
  const float* cond  = (const float*)d_in[1];
  const float* rope  = (const float*)d_in[2];
  const float* w_ada = (const float*)d_in[3];
  const float* w_qkv = (const float*)d_in[4];
  const float* w_out = (const float*)d_in[5];
  const float* qk_w  = (const float*)d_in[6];
  float* out = (float*)d_out;

  char* ws = (char*)d_ws;
  float*          ss   = (float*)ws;                       // 32 KB
  unsigned short* H    = (unsigned short*)(ws + 32768);    // 16 MB, reused as O
  unsigned short* Wq   = H + 8388608;                      // 24 MB
  unsigned short* Wo   = Wq + 12582912;                    // 8 MB  (contiguous after Wq)
  unsigned short* QKV  = Wo + 4194304;                     // 48 MB (q,k used)
  unsigned short* Vt_g = QKV + 25165824;                   // 16 MB

  ada_gemm_kernel<<<2048, 256, 0, stream>>>(cond, w_ada, ss);
  ada_rms_kernel<<<4096, 256, 0, stream>>>(x, ss, H);
  cast2_kernel<<<16384, 256, 0, stream>>>(w_qkv, w_out, Wq);
  // qkv = H @ w_qkv^T ; q,k -> QKV, v -> Vt_g (transposed + k-permuted)
  gemm_bt_kernel<2><<<dim3(48, 32), 256, 0, stream>>>(H, Wq, (void*)QKV, Vt_g, 4096, 6144, 2048);
  qk_rope_kernel<<<32768, 256, 0, stream>>>(QKV, rope, qk_w);
  attn_mfma_kernel<<<512, 256, 0, stream>>>(QKV, Vt_g, H);
  gemm_bt_kernel<0><<<dim3(16, 32), 256, 0, stream>>>(H, Wo, (void*)out, nullptr, 4096, 2048, 2048);
}